// Round 7
// baseline (523.570 us; speedup 1.0000x reference)
//
#include <hip/hip_runtime.h>

#define NN 100000
#define NE 1600000
#define DIM 64
#define NBK 25000   // buckets = dst>>2
#define NSB 98      // ceil(NBK/256)
#define IDXCAP 2176 // LDS-staged entries cap (cnt<=2112 + 64 pad; mean 1024, 34 sigma)

typedef unsigned short u16;
typedef unsigned int u32;

__device__ __forceinline__ u16 f2b(float f) {  // f32 -> bf16 RNE
  union { float f; u32 u; } c; c.f = f;
  u32 u = c.u;
  u += 0x7FFF + ((u >> 16) & 1);
  return (u16)(u >> 16);
}
__device__ __forceinline__ float b2f(u16 h) {
  union { u32 u; float f; } c; c.u = ((u32)h) << 16;
  return c.f;
}
__device__ __forceinline__ float blo(u32 v) {
  union { u32 u; float f; } c; c.u = v << 16;
  return c.f;
}
__device__ __forceinline__ float bhi(u32 v) {
  union { u32 u; float f; } c; c.u = v & 0xFFFF0000u;
  return c.f;
}

// x (f32) -> xh (bf16), 4 elems/thread, exact grid
__global__ __launch_bounds__(256) void k_tobf(const float* __restrict__ x,
                                              u16* __restrict__ xh) {
  int i = blockIdx.x * 256 + threadIdx.x;
  float4 v = ((const float4*)x)[i];
  ushort4 o;
  o.x = f2b(v.x); o.y = f2b(v.y); o.z = f2b(v.z); o.w = f2b(v.w);
  ((ushort4*)xh)[i] = o;
}

// zero dummy row NN of both bf16 buffers (pad entries gather zeros)
__global__ __launch_bounds__(128) void k_zrow(u16* __restrict__ a,
                                              u16* __restrict__ b) {
  int t = threadIdx.x;
  if (t < 64) a[(size_t)NN * DIM + t] = 0;
  else        b[(size_t)NN * DIM + (t - 64)] = 0;
}

// ---- bucket build (dst>>2 granularity) ----

__global__ __launch_bounds__(256) void k_bzero(int* __restrict__ bcnt) {
  int i = blockIdx.x * 256 + threadIdx.x;
  if (i < NBK) bcnt[i] = 0;
}

__global__ __launch_bounds__(256) void k_bhist(const int* __restrict__ ei,
                                               int* __restrict__ bcnt) {
  int e = blockIdx.x * 256 + threadIdx.x;
  atomicAdd(&bcnt[ei[NE + e] >> 2], 1);
}

__global__ __launch_bounds__(256) void k_scan1(const int* __restrict__ bcnt,
                                               int* __restrict__ bstart,
                                               int* __restrict__ bsum) {
  __shared__ int buf[256];
  const int t = threadIdx.x;
  const int i = blockIdx.x * 256 + t;
  int v = (i < NBK) ? bcnt[i] : 0;
  buf[t] = v;
  __syncthreads();
  for (int off = 1; off < 256; off <<= 1) {
    int u = (t >= off) ? buf[t - off] : 0;
    __syncthreads();
    buf[t] += u;
    __syncthreads();
  }
  if (i < NBK) bstart[i] = buf[t] - v;
  if (t == 255) bsum[blockIdx.x] = buf[255];
}

__global__ __launch_bounds__(128) void k_scan2(const int* __restrict__ bsum,
                                               int* __restrict__ boff2) {
  __shared__ int buf[128];
  const int t = threadIdx.x;
  int v = (t < NSB) ? bsum[t] : 0;
  buf[t] = v;
  __syncthreads();
  for (int off = 1; off < 128; off <<= 1) {
    int u = (t >= off) ? buf[t - off] : 0;
    __syncthreads();
    buf[t] += u;
    __syncthreads();
  }
  if (t < NSB) boff2[t] = buf[t] - v;
}

// bcur ALIASES bcnt: read old count first. Last bucket writes bstart[NBK].
__global__ __launch_bounds__(256) void k_scan3(const int* __restrict__ boff2,
                                               int* bstart, int* bcur) {
  int i = blockIdx.x * 256 + threadIdx.x;
  if (i < NBK) {
    int d = bcur[i];  // old count (aliased)
    int s = bstart[i] + boff2[blockIdx.x];
    bstart[i] = s;
    bcur[i] = s;
    if (i == NBK - 1) bstart[NBK] = s + d;  // == NE
  }
}

// scatter packed entries into bucket slots: sequential-in-time per bucket ->
// L2 write-combining (vs 64B-line-per-4B-write of the old per-node fill)
__global__ __launch_bounds__(256) void k_bfill(const int* __restrict__ ei,
                                               int* __restrict__ bcur,
                                               int* __restrict__ bb) {
  int e = blockIdx.x * 256 + threadIdx.x;
  int src = ei[e];
  int dst = ei[NE + e];
  int p = atomicAdd(&bcur[dst >> 2], 1);
  bb[p] = src | ((dst & 63) << 17);  // src < 2^17
}

// ---- fused layer: LDS counting-sort -> bf16 gather (2 edges/load) -> MLP ----
// Block = 16 buckets = 64 nodes, 4 waves. Per row: lanes 0-31 even edges,
// 32-63 odd edges; lane accumulates feature pair {2fl,2fl+1}; combine via
// shfl_xor(32). RACE RULE: xh-in and xh-out differ.
__global__ __launch_bounds__(256) void k_gin(const u16* __restrict__ xh,
                                             const int* __restrict__ bstart,
                                             const int* __restrict__ bb,
                                             const float* __restrict__ eps, int l,
                                             const float* __restrict__ W1,
                                             const float* __restrict__ b1,
                                             const float* __restrict__ W2,
                                             const float* __restrict__ b2,
                                             u16* __restrict__ outh) {
  __shared__ float tile[64 * 65];
  __shared__ int sidx[IDXCAP];
  __shared__ int nhist[64];
  __shared__ int nstart[65];
  __shared__ int ncur[64];
  const int tid = threadIdx.x;
  const int lane = tid & 63;
  const int wv = tid >> 6;
  const int h = lane >> 5;
  const int fl = lane & 31;
  const int base = blockIdx.x * 64;
  const int rows = min(64, NN - base);
  const float sc = 1.0f + eps[l];
  const float sch = (lane < 32) ? sc : 0.0f;
  const u32* xu = (const u32*)xh;

  const int b0 = base >> 2;
  const int s0 = bstart[b0];
  const int cnt = bstart[min(b0 + 16, NBK)] - s0;

  if (tid < 64) nhist[tid] = 0;
  __syncthreads();

  if (cnt <= IDXCAP - 64) {
    // pass 1: per-node histogram (coalesced global read, LDS atomics)
    for (int p = tid; p < cnt; p += 256) {
      atomicAdd(&nhist[bb[s0 + p] >> 17], 1);
    }
    __syncthreads();
    // wave 0: scan even-padded degrees; init cursors; write pad slots
    if (tid < 64) {
      int d0 = nhist[tid];
      int d = (d0 + 1) & ~1;
      int s = d;
#pragma unroll
      for (int off = 1; off < 64; off <<= 1) {
        int u = __shfl_up(s, off, 64);
        if (tid >= off) s += u;
      }
      nstart[tid + 1] = s;
      if (tid == 0) nstart[0] = 0;
      int st = s - d;  // exclusive prefix
      ncur[tid] = st;
      if (d0 & 1) sidx[st + d0] = NN;  // dummy row
    }
    __syncthreads();
    // pass 2: scatter srcs into node-grouped LDS slots
    for (int p = tid; p < cnt; p += 256) {
      int e = bb[s0 + p];
      int pos = atomicAdd(&ncur[e >> 17], 1);
      sidx[pos] = e & 0x1FFFF;
    }
    __syncthreads();

    // gather: 8-deep unroll, 16 edges in flight per wave
    for (int n = wv; n < rows; n += 4) {
      const int a = nstart[n];
      const int m = (nstart[n + 1] - a) >> 1;  // per-half count (even-padded)
      const int off = a + h;
      const int node = base + n;
      u32 us = xu[(size_t)node * 32 + fl];
      float p0 = sch * blo(us), p1 = sch * bhi(us);
      float q0 = 0.f, q1 = 0.f, r0 = 0.f, r1 = 0.f, d0 = 0.f, d1 = 0.f;
      float t0 = 0.f, t1 = 0.f, v0 = 0.f, v1 = 0.f, w0 = 0.f, w1 = 0.f;
      float g0 = 0.f, g1 = 0.f, y0 = 0.f, y1 = 0.f;
      int i = 0;
      for (; i + 7 < m; i += 8) {
        int i0 = sidx[off + 2 * i],      i1 = sidx[off + 2 * i + 2];
        int i2 = sidx[off + 2 * i + 4],  i3 = sidx[off + 2 * i + 6];
        int i4 = sidx[off + 2 * i + 8],  i5 = sidx[off + 2 * i + 10];
        int i6 = sidx[off + 2 * i + 12], i7 = sidx[off + 2 * i + 14];
        u32 u0 = xu[(size_t)i0 * 32 + fl], u1 = xu[(size_t)i1 * 32 + fl];
        u32 u2 = xu[(size_t)i2 * 32 + fl], u3 = xu[(size_t)i3 * 32 + fl];
        u32 u4 = xu[(size_t)i4 * 32 + fl], u5 = xu[(size_t)i5 * 32 + fl];
        u32 u6 = xu[(size_t)i6 * 32 + fl], u7 = xu[(size_t)i7 * 32 + fl];
        p0 += blo(u0); p1 += bhi(u0); q0 += blo(u1); q1 += bhi(u1);
        r0 += blo(u2); r1 += bhi(u2); d0 += blo(u3); d1 += bhi(u3);
        t0 += blo(u4); t1 += bhi(u4); v0 += blo(u5); v1 += bhi(u5);
        w0 += blo(u6); w1 += bhi(u6); g0 += blo(u7); g1 += bhi(u7);
      }
      for (; i < m; ++i) {
        int ix = sidx[off + 2 * i];
        u32 u = xu[(size_t)ix * 32 + fl];
        y0 += blo(u); y1 += bhi(u);
      }
      float e0 = (((p0 + q0) + (r0 + d0)) + ((t0 + v0) + (w0 + g0))) + y0;
      float e1 = (((p1 + q1) + (r1 + d1)) + ((t1 + v1) + (w1 + g1))) + y1;
      e0 += __shfl_xor(e0, 32, 64);
      e1 += __shfl_xor(e1, 32, 64);
      if (lane < 32) {
        tile[n * 65 + 2 * fl] = e0;
        tile[n * 65 + 2 * fl + 1] = e1;
      }
    }
  } else {
    // slow fallback (unreachable statistically): per-node filter over bucket
    for (int n = wv; n < rows; n += 4) {
      const int node = base + n;
      float acc = sc * b2f(xh[(size_t)node * DIM + lane]);
      for (int j = 0; j < cnt; ++j) {
        int e = bb[s0 + j];
        if ((e >> 17) == n) acc += b2f(xh[(size_t)(e & 0x1FFFF) * DIM + lane]);
      }
      tile[n * 65 + lane] = acc;
    }
  }
  __syncthreads();

  // MLP. lane = node row; wave owns cols [jcs, jcs+16), jcs in SGPR.
  const int jcs = __builtin_amdgcn_readfirstlane(wv * 16);
  float acc[16];
#pragma unroll
  for (int j = 0; j < 16; ++j) acc[j] = b1[jcs + j];
#pragma unroll 4
  for (int k = 0; k < 64; ++k) {
    float a = tile[lane * 65 + k];
#pragma unroll
    for (int j = 0; j < 16; ++j) acc[j] = fmaf(a, W1[k * 64 + jcs + j], acc[j]);
  }
  __syncthreads();
#pragma unroll
  for (int j = 0; j < 16; ++j) tile[lane * 65 + jcs + j] = fmaxf(acc[j], 0.0f);
  __syncthreads();

#pragma unroll
  for (int j = 0; j < 16; ++j) acc[j] = b2[jcs + j];
#pragma unroll 4
  for (int k = 0; k < 64; ++k) {
    float a = tile[lane * 65 + k];
#pragma unroll
    for (int j = 0; j < 16; ++j) acc[j] = fmaf(a, W2[k * 64 + jcs + j], acc[j]);
  }
  __syncthreads();
#pragma unroll
  for (int j = 0; j < 16; ++j) tile[lane * 65 + jcs + j] = fmaxf(acc[j], 0.0f);
  __syncthreads();

  for (int n = wv; n < rows; n += 4)
    outh[(size_t)(base + n) * DIM + lane] = f2b(tile[n * 65 + lane]);
}

// out(f32) = bf16_in @ Wf + bf
__global__ __launch_bounds__(256) void k_final(const u16* __restrict__ in,
                                               const float* __restrict__ Wf,
                                               const float* __restrict__ bf,
                                               float* __restrict__ out) {
  __shared__ float tile[64 * 65];
  const int lane = threadIdx.x & 63;
  const int wv = threadIdx.x >> 6;
  const int base = blockIdx.x * 64;
  const int rows = min(64, NN - base);
  const int jcs = __builtin_amdgcn_readfirstlane(wv * 16);

  for (int n = wv; n < rows; n += 4)
    tile[n * 65 + lane] = b2f(in[(size_t)(base + n) * DIM + lane]);
  __syncthreads();

  float acc[16];
#pragma unroll
  for (int j = 0; j < 16; ++j) acc[j] = bf[jcs + j];
#pragma unroll 4
  for (int k = 0; k < 64; ++k) {
    float a = tile[lane * 65 + k];
#pragma unroll
    for (int j = 0; j < 16; ++j) acc[j] = fmaf(a, Wf[k * 64 + jcs + j], acc[j]);
  }
  __syncthreads();
#pragma unroll
  for (int j = 0; j < 16; ++j) tile[lane * 65 + jcs + j] = acc[j];
  __syncthreads();

  for (int n = wv; n < rows; n += 4)
    out[(size_t)(base + n) * DIM + lane] = tile[n * 65 + lane];
}

extern "C" void kernel_launch(void* const* d_in, const int* in_sizes, int n_in,
                              void* d_out, int out_size, void* d_ws, size_t ws_size,
                              hipStream_t stream) {
  const float* x   = (const float*)d_in[0];
  const int*   ei  = (const int*)d_in[1];
  const float* W1  = (const float*)d_in[2];
  const float* b1  = (const float*)d_in[3];
  const float* W2  = (const float*)d_in[4];
  const float* b2  = (const float*)d_in[5];
  const float* eps = (const float*)d_in[6];
  const float* Wf  = (const float*)d_in[7];
  const float* bf  = (const float*)d_in[8];

  // ws: xh0 | xh1 [(NN+1)*64 u16 each] | bb[NE] | bstart[NBK+1] | bcur[NBK]
  //     | bsum[NSB] | boff2[NSB]   (~32.2 MB)
  u16* xh0 = (u16*)d_ws;
  u16* xh1 = xh0 + (size_t)(NN + 1) * DIM;
  int* bb     = (int*)(xh1 + (size_t)(NN + 1) * DIM);
  int* bstart = bb + NE;
  int* bcur   = bstart + NBK + 1;  // aliases bcnt during build
  int* bsum   = bcur + NBK;
  int* boff2  = bsum + NSB;

  const int grid_edges = NE / 256;            // 6250, exact
  const int grid_conv  = NN * DIM / 4 / 256;  // 6250, exact
  const int grid_mlp   = (NN + 63) / 64;      // 1563

  k_tobf<<<grid_conv, 256, 0, stream>>>(x, xh0);
  k_zrow<<<1, 128, 0, stream>>>(xh0, xh1);
  k_bzero<<<NSB, 256, 0, stream>>>(bcur);
  k_bhist<<<grid_edges, 256, 0, stream>>>(ei, bcur);
  k_scan1<<<NSB, 256, 0, stream>>>(bcur, bstart, bsum);
  k_scan2<<<1, 128, 0, stream>>>(bsum, boff2);
  k_scan3<<<NSB, 256, 0, stream>>>(boff2, bstart, bcur);
  k_bfill<<<grid_edges, 256, 0, stream>>>(ei, bcur, bb);

  // bf16 ping-pong: L0 xh0->xh1, L1 xh1->xh0, L2 xh0->xh1, final xh1->d_out
  k_gin<<<grid_mlp, 256, 0, stream>>>(xh0, bstart, bb, eps, 0,
                                      W1, b1, W2, b2, xh1);
  k_gin<<<grid_mlp, 256, 0, stream>>>(xh1, bstart, bb, eps, 1,
                                      W1 + 64 * 64, b1 + 64, W2 + 64 * 64, b2 + 64, xh0);
  k_gin<<<grid_mlp, 256, 0, stream>>>(xh0, bstart, bb, eps, 2,
                                      W1 + 2 * 64 * 64, b1 + 2 * 64, W2 + 2 * 64 * 64, b2 + 2 * 64, xh1);
  k_final<<<grid_mlp, 256, 0, stream>>>(xh1, Wf, bf, (float*)d_out);
}